// Round 11
// baseline (240.503 us; speedup 1.0000x reference)
//
#include <hip/hip_runtime.h>
#include <math.h>

#define B_  256
#define IU  8
#define IC  1152
#define NU  10
#define US  16
#define ROWS 2048   // B_*IU
#define CCH 9
#define NCH 128
#define BT  128      // batches per block
#define NBLK 256     // 128 chunks x 2 b-tiles; 1 block/CU (84 KB static LDS)
#define SPSTRIDE ((size_t)NCH * B_ * NU * US)

// cache-bypassing accessors (coherence point = L3): producer writes that must be
// cross-XCD visible (sp, vb) and small rewritten data (bij).
__device__ __forceinline__ float gld(const float* p) {
    return __hip_atomic_load(p, __ATOMIC_RELAXED, __HIP_MEMORY_SCOPE_AGENT);
}
__device__ __forceinline__ void gst(float* p, float v) {
    __hip_atomic_store(p, v, __ATOMIC_RELAXED, __HIP_MEMORY_SCOPE_AGENT);
}
__device__ __forceinline__ unsigned uld(const unsigned* p) {
    return __hip_atomic_load(p, __ATOMIC_RELAXED, __HIP_MEMORY_SCOPE_AGENT);
}
__device__ __forceinline__ void ust(unsigned* p, unsigned v) {
    __hip_atomic_store(p, v, __ATOMIC_RELAXED, __HIP_MEMORY_SCOPE_AGENT);
}

// ---------------- x transpose: x[b][i][c] -> xT[c][b*8+i] ----------------
__global__ __launch_bounds__(256) void transpose_x(const float* __restrict__ x,
                                                   float* __restrict__ xT) {
    __shared__ float t[32][33];
    const int tx = threadIdx.x & 31, ty = threadIdx.x >> 5;
    const int ct = blockIdx.x % 36;
    const int rt = blockIdx.x / 36;
    const int c0 = ct * 32, r0 = rt * 32;
#pragma unroll
    for (int k = 0; k < 32; k += 8)
        t[ty + k][tx] = x[(size_t)(r0 + ty + k) * IC + c0 + tx];
    __syncthreads();
#pragma unroll
    for (int k = 0; k < 32; k += 8)
        xT[(size_t)(c0 + ty + k) * ROWS + r0 + tx] = t[tx][ty + k];
}

// ---------------- fence-free grid barrier, hierarchical release, 256 blocks ----
// Arrival tree 8x8x4 on 128B-padded lines; release fans out top->4 mids->32 leaves
// (max 8 pollers per line). Line map (x32 u32): leafcnt[l]=l (l<32) | midcnt[h]=64+h
// (h<4) | topcnt=72 | R2[h]=80+h | R1[l]=96+l (l<32). Sleep constants = R9-proven.
__device__ __forceinline__ void gridbar(unsigned* bar) {
    __syncthreads();
    if (threadIdx.x == 0) {
        const int bid = blockIdx.x;
        const int leaf = bid >> 3;        // 0..31
        const int mid  = bid >> 6;        // 0..3
        unsigned* myR1 = bar + (96 + leaf) * 32;
        unsigned g = uld(myR1);
        unsigned a = __hip_atomic_fetch_add(bar + leaf * 32, 1u,
                                            __ATOMIC_RELAXED, __HIP_MEMORY_SCOPE_AGENT);
        if (a == 7u) {
            ust(bar + leaf * 32, 0u);
            unsigned b2 = __hip_atomic_fetch_add(bar + (64 + mid) * 32, 1u,
                                                 __ATOMIC_RELAXED, __HIP_MEMORY_SCOPE_AGENT);
            if (b2 == 7u) {
                ust(bar + (64 + mid) * 32, 0u);
                unsigned c2 = __hip_atomic_fetch_add(bar + 72 * 32, 1u,
                                                     __ATOMIC_RELAXED, __HIP_MEMORY_SCOPE_AGENT);
                if (c2 == 3u) {           // 4 mids
                    ust(bar + 72 * 32, 0u);
#pragma unroll
                    for (int k = 0; k < 4; k++)
                        ust(bar + (80 + k) * 32, g + 1u);
                }
                while (uld(bar + (80 + mid) * 32) == g)
                    __builtin_amdgcn_s_sleep(8);
#pragma unroll
                for (int j = 0; j < 8; j++)
                    ust(bar + (96 + mid * 8 + j) * 32, g + 1u);
            }
        }
        while (uld(myR1) == g)
            __builtin_amdgcn_s_sleep(16);
    }
    __syncthreads();
}

// ---------------- persistent routing kernel v9: BT=128, 256 blocks, static LDS ---
// Block = (c-chunk of 9 channels, b-tile of 128 batches). 8 batches/thread doubles
// W-LDS-read amortization: per-CU s-phase ds_read_b128 wave-instrs 2016 -> 1296.
__global__ __launch_bounds__(256, 1) void mega(const float* __restrict__ xT,
                                               const float* __restrict__ W,
                                               float* __restrict__ sp,     // 3 buffers
                                               float* __restrict__ vb0,
                                               float* __restrict__ vb1,
                                               float* __restrict__ bij,
                                               float* __restrict__ out,
                                               unsigned* __restrict__ bar) {
    __shared__ float4 ws[CCH * NU * 2 * 16];            // 46080 B [cc][d][h][uq]
    __shared__ __align__(16) float xs[CCH * BT * IU];   // 36864 B [cc][bl][i]
    __shared__ float aux[NU * US];                      // 640 B (squash s-vector)
    __shared__ float cs[NU * CCH];                      // 360 B (c_ij slice)
    // total static LDS: 83,944 B -> 1 block/CU, 4 waves

    const int tid = threadIdx.x;
    const int bid = blockIdx.x;
    const int grp = bid & 7;
    const int slot_ = bid >> 3;                 // 0..31
    const int ch = ((slot_ >> 1) << 3) | grp;   // 0..127, chunk pinned to one XCD
    const int bt = slot_ & 1;
    const int b0 = bt * BT, c0 = ch * CCH;

    // ---- one-time staging (plain cached loads: read-only inputs) ----
    const float4* wg = (const float4*)W + (size_t)c0 * 320;
    for (int q = tid; q < CCH * NU * 32; q += 256) {
        int h = q & 1, u = (q >> 1) & 15, cd = q >> 5;
        ws[(cd * 2 + h) * 16 + u] = wg[q];
    }
    const float4* xg = (const float4*)xT;
    float4* xsv = (float4*)xs;
    for (int q = tid; q < CCH * BT * 2; q += 256) {     // 2304 float4
        int cc = q >> 8, r = q & 255;
        xsv[cc * 256 + r] = xg[(size_t)(c0 + cc) * (ROWS / 4) + b0 * 2 + r];
    }

    const int uq = tid & 15;
    const int bs = tid >> 4;      // 0..15
    const int wv = tid >> 6;      // wave id 0..3
    const int lane = tid & 63;

    for (int iter = 0; iter < 3; ++iter) {
        float* spb = sp + (size_t)iter * SPSTRIDE;

        // ---- c_ij slice: uniform (iter 0) or per-block softmax of b_ij rows ----
        __syncthreads();
        if (iter == 0) {
            for (int q = tid; q < NU * CCH; q += 256) cs[q] = 1.0f;
        } else {
            for (int d = wv; d < NU; d += 4) {
                const float* brow = bij + (size_t)d * IC;
                float bv[18];
                float mx = -1e30f;
#pragma unroll
                for (int j = 0; j < 18; j++) {
                    bv[j] = gld(brow + lane + j * 64);
                    mx = fmaxf(mx, bv[j]);
                }
#pragma unroll
                for (int off = 32; off > 0; off >>= 1)
                    mx = fmaxf(mx, __shfl_xor(mx, off, 64));
                float sume = 0.0f;
#pragma unroll
                for (int j = 0; j < 18; j++) sume += expf(bv[j] - mx);
#pragma unroll
                for (int off = 32; off > 0; off >>= 1)
                    sume += __shfl_xor(sume, off, 64);
                const float inv = 1.0f / sume;
                if (lane < CCH)
                    cs[d * CCH + lane] = expf(gld(brow + c0 + lane) - mx) * inv;
            }
        }
        __syncthreads();
        const float scale = iter ? 1.0f : (1.0f / (float)IC);   // softmax(0) uniform

        // ---- s phase: thread (uq, bs) x 8 bb, all 10 d ----
        {
            float acc[8][NU];
#pragma unroll
            for (int bb = 0; bb < 8; bb++)
#pragma unroll
                for (int d = 0; d < NU; d++) acc[bb][d] = 0.0f;

#pragma unroll 3
            for (int cc = 0; cc < CCH; cc++) {
                float4 xv0[8], xv1[8];
#pragma unroll
                for (int bb = 0; bb < 8; bb++) {
                    const float4* xp = (const float4*)(xs + (cc * BT + bs + 16 * bb) * IU);
                    xv0[bb] = xp[0]; xv1[bb] = xp[1];
                }
#pragma unroll
                for (int d = 0; d < NU; d++) {
                    float4 w0 = ws[((cc * NU + d) * 2 + 0) * 16 + uq];
                    float4 w1 = ws[((cc * NU + d) * 2 + 1) * 16 + uq];
                    const float cw = cs[d * CCH + cc];
#pragma unroll
                    for (int bb = 0; bb < 8; bb++) {
                        float uh = w0.x * xv0[bb].x + w0.y * xv0[bb].y + w0.z * xv0[bb].z + w0.w * xv0[bb].w
                                 + w1.x * xv1[bb].x + w1.y * xv1[bb].y + w1.z * xv1[bb].z + w1.w * xv1[bb].w;
                        acc[bb][d] = fmaf(cw, uh, acc[bb][d]);
                    }
                }
            }
#pragma unroll
            for (int bb = 0; bb < 8; bb++) {
                const int b = b0 + bs + 16 * bb;
#pragma unroll
                for (int d = 0; d < NU; d++)
                    gst(spb + (((size_t)ch * B_ + b) * NU + d) * US + uq, acc[bb][d] * scale);
            }
        }
        gridbar(bar);

        // ---- squash: ALL 256 blocks, one batch each. spb write-once-read-once
        //      per launch -> cached float4 loads; part-combine via shfl. ----
        {
            const int batch = bid;
            if (tid < 160) {
                const int part = tid & 3;     // 4 chunk-quarters in adjacent lanes
                const int sl = tid >> 2;      // float4 slot 0..39
                const float4* s4p = (const float4*)spb;
                float4 a = make_float4(0.f, 0.f, 0.f, 0.f);
#pragma unroll 8
                for (int k = 0; k < 32; ++k) {
                    float4 t = s4p[((size_t)(part * 32 + k) * B_ + batch) * 40 + sl];
                    a.x += t.x; a.y += t.y; a.z += t.z; a.w += t.w;
                }
                a.x += __shfl_xor(a.x, 1, 64); a.y += __shfl_xor(a.y, 1, 64);
                a.z += __shfl_xor(a.z, 1, 64); a.w += __shfl_xor(a.w, 1, 64);
                a.x += __shfl_xor(a.x, 2, 64); a.y += __shfl_xor(a.y, 2, 64);
                a.z += __shfl_xor(a.z, 2, 64); a.w += __shfl_xor(a.w, 2, 64);
                if (part == 0) {
                    aux[sl * 4 + 0] = a.x; aux[sl * 4 + 1] = a.y;
                    aux[sl * 4 + 2] = a.z; aux[sl * 4 + 3] = a.w;
                }
            }
            __syncthreads();
            if (tid < NU * US) {
                float s = aux[tid];
                float msq = 0.0f;
#pragma unroll
                for (int dd = 0; dd < NU; dd++) {
                    float t = aux[dd * US + uq];
                    msq = fmaf(t, t, msq);
                }
                float f = msq / ((1.0f + msq) * sqrtf(msq));
                if (iter == 2)
                    out[(size_t)batch * (NU * US) + tid] = s * f;   // kernel-end flush
                else {
                    float* vdst = (iter == 0) ? vb0 : vb1;
                    gst(vdst + (size_t)batch * (NU * US) + tid, s * f);
                }
            }
        }
        if (iter == 2) return;
        gridbar(bar);

        // ---- agree: thread (uq, cl<9); W from LDS regs, 128 b streamed;
        //      vb cached (write-once-read-once per launch). ----
        {
            const int cl = tid >> 4;
            const float* vb = (iter == 0) ? vb0 : vb1;
            if (cl < CCH) {
                float4 wA[NU], wB[NU];
#pragma unroll
                for (int d = 0; d < NU; d++) {
                    wA[d] = ws[((cl * NU + d) * 2 + 0) * 16 + uq];
                    wB[d] = ws[((cl * NU + d) * 2 + 1) * 16 + uq];
                }
                float accd[NU];
#pragma unroll
                for (int d = 0; d < NU; d++) accd[d] = 0.0f;
                const int bstag = (cl & 3) * 7;   // de-conflict xs reads across cl
#pragma unroll 4
                for (int blx = 0; blx < BT; blx++) {
                    const int bl = (blx + bstag) & (BT - 1);
                    const float* xp = xs + (cl * BT + bl) * IU;
                    float4 x0 = *(const float4*)xp;
                    float4 x1 = *(const float4*)(xp + 4);
                    const float* vp = vb + (size_t)(b0 + bl) * (NU * US) + uq;
#pragma unroll
                    for (int d = 0; d < NU; d++) {
                        float uh = wA[d].x * x0.x + wA[d].y * x0.y + wA[d].z * x0.z + wA[d].w * x0.w
                                 + wB[d].x * x1.x + wB[d].y * x1.y + wB[d].z * x1.z + wB[d].w * x1.w;
                        accd[d] = fmaf(uh, vp[d * US], accd[d]);
                    }
                }
#pragma unroll
                for (int d = 0; d < NU; d++) {
                    float a = accd[d];
                    a += __shfl_xor(a, 1, 64);
                    a += __shfl_xor(a, 2, 64);
                    a += __shfl_xor(a, 4, 64);
                    a += __shfl_xor(a, 8, 64);
                    if (uq == 0)
                        atomicAdd(bij + (size_t)d * IC + c0 + cl, a * (1.0f / (float)B_));
                }
            }
        }
        gridbar(bar);
    }
}

extern "C" void kernel_launch(void* const* d_in, const int* in_sizes, int n_in,
                              void* d_out, int out_size, void* d_ws, size_t ws_size,
                              hipStream_t stream) {
    (void)in_sizes; (void)n_in; (void)out_size; (void)ws_size;
    const float* x = (const float*)d_in[0];   // [256, 8, 1152]
    const float* W = (const float*)d_in[1];   // [1, 1152, 10, 16, 8]
    float* out = (float*)d_out;               // [256, 10, 16] fp32

    // workspace: bar (20 KB) | bij | xT | sp x3 | vb0 | vb1   (~73 MiB)
    unsigned* bar = (unsigned*)d_ws;
    float* bij = (float*)d_ws + 5120;
    float* xT  = bij + (size_t)NU * IC;
    float* sp  = xT + (size_t)IC * ROWS;
    float* vb0 = sp + 3 * SPSTRIDE;
    float* vb1 = vb0 + (size_t)B_ * NU * US;

    hipMemsetAsync(d_ws, 0, 5120 * 4 + (size_t)NU * IC * 4, stream);  // bar + bij
    transpose_x<<<36 * 64, 256, 0, stream>>>(x, xT);
    mega<<<NBLK, 256, 0, stream>>>(xT, W, sp, vb0, vb1, bij, out, bar);
}

// Round 12
// 193.148 us; speedup vs baseline: 1.2452x; 1.2452x over previous
//
#include <hip/hip_runtime.h>
#include <math.h>

#define B_  256
#define IU  8
#define IC  1152
#define NU  10
#define US  16
#define CCH 9
#define NCH 128
#define BT  64
#define NBLK 512
#define SPSTRIDE ((size_t)NCH * B_ * NU * US)   // floats per sp buffer

// cache-bypassing accessors (coherence point = L3): producer writes that must be
// cross-XCD visible (sp, vb) and small rewritten data (bij).
__device__ __forceinline__ float gld(const float* p) {
    return __hip_atomic_load(p, __ATOMIC_RELAXED, __HIP_MEMORY_SCOPE_AGENT);
}
__device__ __forceinline__ void gst(float* p, float v) {
    __hip_atomic_store(p, v, __ATOMIC_RELAXED, __HIP_MEMORY_SCOPE_AGENT);
}
__device__ __forceinline__ unsigned uld(const unsigned* p) {
    return __hip_atomic_load(p, __ATOMIC_RELAXED, __HIP_MEMORY_SCOPE_AGENT);
}
__device__ __forceinline__ void ust(unsigned* p, unsigned v) {
    __hip_atomic_store(p, v, __ATOMIC_RELAXED, __HIP_MEMORY_SCOPE_AGENT);
}

// ---------------- fence-free grid barrier, hierarchical release (R8/R9 proven) --
// Arrival tree 8x8x8 on 128B-padded lines; release fans out top->8 mids->64 leaves
// (max 8 pollers per line). Line map (x32 u32): leafcnt[l]=l (l<64) | midcnt[h]=64+h
// | topcnt=72 | R2[h]=80+h | R1[l]=96+l.
__device__ __forceinline__ void gridbar(unsigned* bar) {
    __syncthreads();
    if (threadIdx.x == 0) {
        const int bid = blockIdx.x;
        const int leaf = bid >> 3;        // 0..63
        const int mid  = bid >> 6;        // 0..7
        unsigned* myR1 = bar + (96 + leaf) * 32;
        unsigned g = uld(myR1);
        unsigned a = __hip_atomic_fetch_add(bar + leaf * 32, 1u,
                                            __ATOMIC_RELAXED, __HIP_MEMORY_SCOPE_AGENT);
        if (a == 7u) {
            ust(bar + leaf * 32, 0u);
            unsigned b2 = __hip_atomic_fetch_add(bar + (64 + mid) * 32, 1u,
                                                 __ATOMIC_RELAXED, __HIP_MEMORY_SCOPE_AGENT);
            if (b2 == 7u) {
                ust(bar + (64 + mid) * 32, 0u);
                unsigned c2 = __hip_atomic_fetch_add(bar + 72 * 32, 1u,
                                                     __ATOMIC_RELAXED, __HIP_MEMORY_SCOPE_AGENT);
                if (c2 == 7u) {
                    ust(bar + 72 * 32, 0u);
#pragma unroll
                    for (int k = 0; k < 8; k++)
                        ust(bar + (80 + k) * 32, g + 1u);
                }
                while (uld(bar + (80 + mid) * 32) == g)
                    __builtin_amdgcn_s_sleep(8);
#pragma unroll
                for (int j = 0; j < 8; j++)
                    ust(bar + (96 + mid * 8 + j) * 32, g + 1u);
            }
        }
        while (uld(myR1) == g)
            __builtin_amdgcn_s_sleep(16);
    }
    __syncthreads();
}

// ---------------- persistent routing kernel v10 (= R9 + fused x staging) --------
// Block = (c-chunk of 9 channels, b-tile of 64). W+x staged in LDS once, reused by
// 3 s-phases + 2 agree-phases. 7 grid barriers. sp triple-buffered, vb0/vb1
// double-buffered -> squash & agree read via the normal cached path.
__global__ __launch_bounds__(256, 2) void mega(const float* __restrict__ x,
                                               const float* __restrict__ W,
                                               float* __restrict__ sp,     // 3 buffers
                                               float* __restrict__ vb0,
                                               float* __restrict__ vb1,
                                               float* __restrict__ bij,
                                               float* __restrict__ out,
                                               unsigned* __restrict__ bar) {
    __shared__ float4 ws[CCH * NU * 2 * 16];            // 46080 B raw W [cc][d][h][uq]
    __shared__ __align__(16) float xs[CCH * BT * IU];   // 18432 B  [cc][bl][i]
    __shared__ float aux[NU * US];                      // 640 B (squash s-vector)
    __shared__ float cs[NU * CCH];                      // 360 B (c_ij slice)

    const int tid = threadIdx.x;
    const int bid = blockIdx.x;
    const int grp = bid & 7;
    const int slot_ = bid >> 3;
    const int ch = ((slot_ >> 2) << 3) | grp;   // chunk pinned to one XCD (perf-only)
    const int bt = slot_ & 3;
    const int b0 = bt * BT, c0 = ch * CCH;

    // ---- one-time staging (plain cached loads: read-only inputs) ----
    const float4* wg = (const float4*)W + (size_t)c0 * 320;
    for (int q = tid; q < CCH * NU * 32; q += 256) {
        int h = q & 1, u = (q >> 1) & 15, cd = q >> 5;
        ws[(cd * 2 + h) * 16 + u] = wg[q];
    }
    // x staged directly from native [b][i][c]: idx -> (row r = bl*8+i, cc).
    // Reads: 9-float row segments (~7 lines/wave-instr); each x element staged
    // exactly once grid-wide. LDS write 9-way conflict costs ~0.3 us once.
    for (int idx = tid; idx < CCH * BT * IU; idx += 256) {
        int cc = idx % CCH;
        int r = idx / CCH;                       // r = bl*8 + i
        xs[cc * (BT * IU) + r] = x[((size_t)(b0 + (r >> 3)) * IU + (r & 7)) * IC + c0 + cc];
    }

    const int uq = tid & 15;
    const int bs = tid >> 4;
    const int wv = tid >> 6;      // wave id 0..3
    const int lane = tid & 63;

    for (int iter = 0; iter < 3; ++iter) {
        float* spb = sp + (size_t)iter * SPSTRIDE;   // this iteration's buffer

        // ---- c_ij slice: uniform (iter 0) or per-block softmax of b_ij rows ----
        __syncthreads();
        if (iter == 0) {
            for (int q = tid; q < NU * CCH; q += 256) cs[q] = 1.0f;
        } else {
            for (int d = wv; d < NU; d += 4) {
                const float* brow = bij + (size_t)d * IC;
                float bv[18];
                float mx = -1e30f;
#pragma unroll
                for (int j = 0; j < 18; j++) {
                    bv[j] = gld(brow + lane + j * 64);
                    mx = fmaxf(mx, bv[j]);
                }
#pragma unroll
                for (int off = 32; off > 0; off >>= 1)
                    mx = fmaxf(mx, __shfl_xor(mx, off, 64));
                float sume = 0.0f;
#pragma unroll
                for (int j = 0; j < 18; j++) sume += expf(bv[j] - mx);
#pragma unroll
                for (int off = 32; off > 0; off >>= 1)
                    sume += __shfl_xor(sume, off, 64);
                const float inv = 1.0f / sume;
                if (lane < CCH)
                    cs[d * CCH + lane] = expf(gld(brow + c0 + lane) - mx) * inv;
            }
        }
        __syncthreads();
        const float scale = iter ? 1.0f : (1.0f / (float)IC);   // softmax(0) uniform

        // ---- s phase ----
        {
            float acc[4][NU];
#pragma unroll
            for (int bb = 0; bb < 4; bb++)
#pragma unroll
                for (int d = 0; d < NU; d++) acc[bb][d] = 0.0f;

#pragma unroll 3
            for (int cc = 0; cc < CCH; cc++) {
                float4 xv0[4], xv1[4];
#pragma unroll
                for (int bb = 0; bb < 4; bb++) {
                    const float4* xp = (const float4*)(xs + (cc * BT + bs + 16 * bb) * IU);
                    xv0[bb] = xp[0]; xv1[bb] = xp[1];
                }
#pragma unroll
                for (int d = 0; d < NU; d++) {
                    float4 w0 = ws[((cc * NU + d) * 2 + 0) * 16 + uq];
                    float4 w1 = ws[((cc * NU + d) * 2 + 1) * 16 + uq];
                    const float cw = cs[d * CCH + cc];
#pragma unroll
                    for (int bb = 0; bb < 4; bb++) {
                        float uh = w0.x * xv0[bb].x + w0.y * xv0[bb].y + w0.z * xv0[bb].z + w0.w * xv0[bb].w
                                 + w1.x * xv1[bb].x + w1.y * xv1[bb].y + w1.z * xv1[bb].z + w1.w * xv1[bb].w;
                        acc[bb][d] = fmaf(cw, uh, acc[bb][d]);
                    }
                }
            }
#pragma unroll
            for (int bb = 0; bb < 4; bb++) {
                const int b = b0 + bs + 16 * bb;
#pragma unroll
                for (int d = 0; d < NU; d++)
                    gst(spb + (((size_t)ch * B_ + b) * NU + d) * US + uq, acc[bb][d] * scale);
            }
        }
        gridbar(bar);

        // ---- squash: blocks 0..255, one batch each. spb is write-once-read-once
        //      per launch -> PLAIN CACHED float4 loads; part-combine via shfl. ----
        if (bid < B_) {
            if (tid < 160) {
                const int part = tid & 3;     // 4 chunk-quarters in adjacent lanes
                const int sl = tid >> 2;      // float4 slot 0..39 of the 160-vec
                const float4* s4p = (const float4*)spb;
                float4 a = make_float4(0.f, 0.f, 0.f, 0.f);
#pragma unroll 8
                for (int k = 0; k < 32; ++k) {
                    float4 t = s4p[((size_t)(part * 32 + k) * B_ + bid) * 40 + sl];
                    a.x += t.x; a.y += t.y; a.z += t.z; a.w += t.w;
                }
                a.x += __shfl_xor(a.x, 1, 64); a.y += __shfl_xor(a.y, 1, 64);
                a.z += __shfl_xor(a.z, 1, 64); a.w += __shfl_xor(a.w, 1, 64);
                a.x += __shfl_xor(a.x, 2, 64); a.y += __shfl_xor(a.y, 2, 64);
                a.z += __shfl_xor(a.z, 2, 64); a.w += __shfl_xor(a.w, 2, 64);
                if (part == 0) {
                    aux[sl * 4 + 0] = a.x; aux[sl * 4 + 1] = a.y;
                    aux[sl * 4 + 2] = a.z; aux[sl * 4 + 3] = a.w;
                }
            }
            __syncthreads();
            if (tid < NU * US) {
                float s = aux[tid];
                float msq = 0.0f;
#pragma unroll
                for (int dd = 0; dd < NU; dd++) {
                    float t = aux[dd * US + uq];
                    msq = fmaf(t, t, msq);
                }
                float f = msq / ((1.0f + msq) * sqrtf(msq));
                if (iter == 2)
                    out[(size_t)bid * (NU * US) + tid] = s * f;   // kernel-end flush
                else {
                    float* vdst = (iter == 0) ? vb0 : vb1;
                    gst(vdst + (size_t)bid * (NU * US) + tid, s * f);
                }
            }
        }
        if (iter == 2) return;
        gridbar(bar);

        // ---- agree phase: thread (uq, cl<9); W from LDS regs, 64 b streamed.
        //      vb is write-once-read-once per launch -> PLAIN CACHED loads. ----
        {
            const int cl = tid >> 4;
            const float* vb = (iter == 0) ? vb0 : vb1;
            if (cl < CCH) {
                float4 wA[NU], wB[NU];
#pragma unroll
                for (int d = 0; d < NU; d++) {
                    wA[d] = ws[((cl * NU + d) * 2 + 0) * 16 + uq];
                    wB[d] = ws[((cl * NU + d) * 2 + 1) * 16 + uq];
                }
                float accd[NU];
#pragma unroll
                for (int d = 0; d < NU; d++) accd[d] = 0.0f;
                const int bstag = (cl & 3) * 7;   // de-conflict xs reads across cl
#pragma unroll 4
                for (int blx = 0; blx < BT; blx++) {
                    const int bl = (blx + bstag) & 63;
                    const float* xp = xs + (cl * BT + bl) * IU;
                    float4 x0 = *(const float4*)xp;
                    float4 x1 = *(const float4*)(xp + 4);
                    const float* vp = vb + (size_t)(b0 + bl) * (NU * US) + uq;
#pragma unroll
                    for (int d = 0; d < NU; d++) {
                        float uh = wA[d].x * x0.x + wA[d].y * x0.y + wA[d].z * x0.z + wA[d].w * x0.w
                                 + wB[d].x * x1.x + wB[d].y * x1.y + wB[d].z * x1.z + wB[d].w * x1.w;
                        accd[d] = fmaf(uh, vp[d * US], accd[d]);
                    }
                }
#pragma unroll
                for (int d = 0; d < NU; d++) {
                    float a = accd[d];
                    a += __shfl_xor(a, 1, 64);
                    a += __shfl_xor(a, 2, 64);
                    a += __shfl_xor(a, 4, 64);
                    a += __shfl_xor(a, 8, 64);
                    if (uq == 0)
                        atomicAdd(bij + (size_t)d * IC + c0 + cl, a * (1.0f / (float)B_));
                }
            }
        }
        gridbar(bar);
    }
}

extern "C" void kernel_launch(void* const* d_in, const int* in_sizes, int n_in,
                              void* d_out, int out_size, void* d_ws, size_t ws_size,
                              hipStream_t stream) {
    (void)in_sizes; (void)n_in; (void)out_size; (void)ws_size;
    const float* x = (const float*)d_in[0];   // [256, 8, 1152]
    const float* W = (const float*)d_in[1];   // [1, 1152, 10, 16, 8]
    float* out = (float*)d_out;               // [256, 10, 16] fp32

    // workspace: bar (20 KB) | bij | sp x3 | vb0 | vb1   (~63 MiB)
    unsigned* bar = (unsigned*)d_ws;
    float* bij = (float*)d_ws + 5120;
    float* sp  = bij + (size_t)NU * IC;
    float* vb0 = sp + 3 * SPSTRIDE;
    float* vb1 = vb0 + (size_t)B_ * NU * US;

    hipMemsetAsync(d_ws, 0, 5120 * 4 + (size_t)NU * IC * 4, stream);  // bar + bij
    mega<<<NBLK, 256, 0, stream>>>(x, W, sp, vb0, vb1, bij, out, bar);
}